// Round 1
// 743.686 us; speedup vs baseline: 1.0385x; 1.0385x over previous
//
#include <hip/hip_runtime.h>

#define N_NODES 100000
#define N_EDGES 3200000
#define F 256

#define BM 128
#define BN 256
#define BK 32

#define SCAN_NB ((N_NODES + 255) / 256)   // 391 blocks of 256
#define EDGE_NB (N_EDGES / 256)           // 12500 blocks, exact

typedef __attribute__((ext_vector_type(8))) short short8;
typedef __attribute__((ext_vector_type(4))) float f32x4;

__device__ inline unsigned short f2bf(float f) {
    unsigned int u = __float_as_uint(f);
    unsigned int r = (u + 0x7fffu + ((u >> 16) & 1u)) >> 16;
    return (unsigned short)r;
}

__device__ inline float bf2f(unsigned short b) {
    return __uint_as_float(((unsigned int)b) << 16);
}

// ---------------------------------------------------------------------------
// Weight transpose + convert: Wt[n][k] = bf16(W[k][n]). 256x256, tiny.
// ---------------------------------------------------------------------------
__global__ void wt_kernel(const float* __restrict__ W, unsigned short* __restrict__ Wt) {
    int idx = blockIdx.x * 256 + threadIdx.x;
    int n = idx >> 8;
    int k = idx & 255;
    Wt[n * 256 + k] = f2bf(W[k * 256 + n]);
}

// ---------------------------------------------------------------------------
// CSR build step 1: degree histogram AND per-edge rank (the atomic's return
// value). rank is what lets fill_kernel run atomic-free. One thread per edge.
// ---------------------------------------------------------------------------
__global__ __launch_bounds__(256)
void rank_hist_kernel(const int* __restrict__ dst, int* __restrict__ counts,
                      unsigned short* __restrict__ rank) {
    const int e = blockIdx.x * 256 + threadIdx.x;
    rank[e] = (unsigned short)atomicAdd(&counts[dst[e]], 1);
}

// ---------------------------------------------------------------------------
// CSR build step 2a: per-block exclusive scan (256 elems/block) + block totals
// ---------------------------------------------------------------------------
__global__ __launch_bounds__(256)
void scan1_kernel(const int* __restrict__ counts, int* __restrict__ row_start,
                  int* __restrict__ partials) {
    __shared__ int s[256];
    const int t = threadIdx.x;
    const int i = blockIdx.x * 256 + t;
    int v = (i < N_NODES) ? counts[i] : 0;
    s[t] = v;
    __syncthreads();
#pragma unroll
    for (int off = 1; off < 256; off <<= 1) {
        int x = (t >= off) ? s[t - off] : 0;
        __syncthreads();
        if (t >= off) s[t] += x;
        __syncthreads();
    }
    if (i < N_NODES) row_start[i] = s[t] - v;
    if (t == 255) partials[blockIdx.x] = s[t];
}

// ---------------------------------------------------------------------------
// CSR build step 2b: scan the 391 block totals (single block, 512 threads)
// ---------------------------------------------------------------------------
__global__ __launch_bounds__(512)
void scan2_kernel(int* __restrict__ partials) {
    __shared__ int s[512];
    const int t = threadIdx.x;
    int v = (t < SCAN_NB) ? partials[t] : 0;
    s[t] = v;
    __syncthreads();
#pragma unroll
    for (int off = 1; off < 512; off <<= 1) {
        int x = (t >= off) ? s[t - off] : 0;
        __syncthreads();
        if (t >= off) s[t] += x;
        __syncthreads();
    }
    if (t < SCAN_NB) partials[t] = s[t] - v;
}

// ---------------------------------------------------------------------------
// CSR build step 2c: add block offsets.
// ---------------------------------------------------------------------------
__global__ __launch_bounds__(256)
void scan3_kernel(int* __restrict__ row_start, const int* __restrict__ partials) {
    const int i = blockIdx.x * 256 + threadIdx.x;
    if (i < N_NODES)
        row_start[i] += partials[blockIdx.x];
    if (i == 0) row_start[N_NODES] = N_EDGES;
}

// ---------------------------------------------------------------------------
// CSR build step 3: place packed (src, val) records at row_start[d] + rank[e].
// No atomics: pure loads + one scattered 8B store per edge.
// ---------------------------------------------------------------------------
__global__ __launch_bounds__(256)
void fill_kernel(const int* __restrict__ src, const int* __restrict__ dst,
                 const float* __restrict__ val,
                 const int* __restrict__ row_start,
                 const unsigned short* __restrict__ rank,
                 int2* __restrict__ recs) {
    const int e = blockIdx.x * 256 + threadIdx.x;
    const int d = dst[e];
    const int pos = row_start[d] + (int)rank[e];
    recs[pos] = make_int2(src[e], __float_as_int(val[e]));
}

// ---------------------------------------------------------------------------
// GEMM: out[n, 0:256] = input[n, :] @ W  (fp32 result) and a compact bf16
// copy ftb[n][256] for the gather stage (51 MB, L3-resident random-read set).
// BN=256: whole output width in one pass -> A is fetched+converted ONCE
// (grid.y=2 split re-fetched A ~half a grid apart, missing L2).
// ---------------------------------------------------------------------------
__global__ __launch_bounds__(256, 2)
void gemm_kernel(const float* __restrict__ A,
                 const unsigned short* __restrict__ Wt,
                 float* __restrict__ out,
                 unsigned short* __restrict__ ftb)
{
    __shared__ unsigned short As[BM * BK];   // 8 KB
    __shared__ unsigned short Bs[BN * BK];   // 16 KB

    const int tid   = threadIdx.x;
    const int lane  = tid & 63;
    const int wave  = tid >> 6;
    const int waveM = wave >> 1;             // 0..1 : 64-row half
    const int waveN = wave & 1;              // 0..1 : 128-col half
    const int rowBase = blockIdx.x * BM;

    f32x4 acc[4][8];
#pragma unroll
    for (int i = 0; i < 4; i++)
#pragma unroll
        for (int j = 0; j < 8; j++) acc[i][j] = (f32x4)0.0f;

    const int sr = tid >> 2;        // 0..63
    const int sk = (tid & 3) * 8;   // 0,8,16,24
    const int quad = lane >> 4;
    const int l16  = lane & 15;

    for (int kt = 0; kt < 8; kt++) {
        const int k0 = kt * BK;
        // A tile: 128 rows x 32 cols, fp32 -> bf16 convert
#pragma unroll
        for (int p = 0; p < 2; p++) {
            const int r = p * 64 + sr;
            const int grow = rowBase + r;
            short8 av;
            if (grow < N_NODES) {
                const float4* pa = (const float4*)(A + (size_t)grow * 256 + k0 + sk);
                float4 f0 = pa[0];
                float4 f1 = pa[1];
                av[0] = (short)f2bf(f0.x); av[1] = (short)f2bf(f0.y);
                av[2] = (short)f2bf(f0.z); av[3] = (short)f2bf(f0.w);
                av[4] = (short)f2bf(f1.x); av[5] = (short)f2bf(f1.y);
                av[6] = (short)f2bf(f1.z); av[7] = (short)f2bf(f1.w);
            } else {
                av = (short8)0;
            }
            *(short8*)(&As[r * BK + sk]) = av;
        }
        // B tile: 256 rows (output cols) x 32
#pragma unroll
        for (int p = 0; p < 4; p++) {
            const int r = p * 64 + sr;
            const uint4 wv = *(const uint4*)(Wt + (size_t)r * 256 + k0 + sk);
            *(uint4*)(&Bs[r * BK + sk]) = wv;
        }
        __syncthreads();

        short8 af[4], bfr[8];
#pragma unroll
        for (int i = 0; i < 4; i++)
            af[i] = *(const short8*)(&As[(waveM * 64 + i * 16 + l16) * BK + quad * 8]);
#pragma unroll
        for (int j = 0; j < 8; j++)
            bfr[j] = *(const short8*)(&Bs[(waveN * 128 + j * 16 + l16) * BK + quad * 8]);
#pragma unroll
        for (int i = 0; i < 4; i++)
#pragma unroll
            for (int j = 0; j < 8; j++)
                acc[i][j] = __builtin_amdgcn_mfma_f32_16x16x32_bf16(
                    af[i], bfr[j], acc[i][j], 0, 0, 0);
        __syncthreads();
    }

    const int colBase = waveN * 128;
#pragma unroll
    for (int i = 0; i < 4; i++) {
        const int row0 = rowBase + waveM * 64 + i * 16 + quad * 4;
#pragma unroll
        for (int j = 0; j < 8; j++) {
            const int col = colBase + j * 16 + l16;
#pragma unroll
            for (int r = 0; r < 4; r++) {
                const int row = row0 + r;
                if (row < N_NODES) {
                    float v = acc[i][j][r];
                    out[(size_t)row * 512 + col] = v;
                    ftb[(size_t)row * 256 + col] = f2bf(v);
                }
            }
        }
    }
}

// ---------------------------------------------------------------------------
// Gather: one wave per dst node. out[n, 256:512] = sum_e val_e * ftb[src_e]
// 8-edge unroll (8 outstanding 512B row reads/wave) + software prefetch of
// the next iteration's recs octet so the record-read latency hides under the
// current iteration's row loads. Latency-bound -> MLP is the lever.
// Accumulation stays in ascending edge order: bitwise-identical result.
// ---------------------------------------------------------------------------
__global__ __launch_bounds__(256)
void gather_kernel(const int* __restrict__ row_start,
                   const int2* __restrict__ recs,
                   const unsigned short* __restrict__ ftb,
                   float* __restrict__ out)
{
    const int n = blockIdx.x * 4 + (threadIdx.x >> 6);
    if (n >= N_NODES) return;
    const int lane = threadIdx.x & 63;

    const int beg = row_start[n];
    const int end = row_start[n + 1];

    float ax = 0.f, ay = 0.f, az = 0.f, aw = 0.f;

    int e = beg;

    if (e + 7 < end) {
        int2 r[8];
#pragma unroll
        for (int q = 0; q < 8; q++) r[q] = recs[e + q];
        while (true) {
            const int en = e + 8;
            const bool moreN = (en + 7 < end);
            int2 rn[8];
            if (moreN) {
#pragma unroll
                for (int q = 0; q < 8; q++) rn[q] = recs[en + q];
            }
            ushort4 u[8];
#pragma unroll
            for (int q = 0; q < 8; q++)
                u[q] = *(const ushort4*)(ftb + (size_t)r[q].x * 256 + lane * 4);
#pragma unroll
            for (int q = 0; q < 8; q++) {
                const float v = __int_as_float(r[q].y);
                ax += v * bf2f(u[q].x); ay += v * bf2f(u[q].y);
                az += v * bf2f(u[q].z); aw += v * bf2f(u[q].w);
            }
            e = en;
            if (!moreN) break;
#pragma unroll
            for (int q = 0; q < 8; q++) r[q] = rn[q];
        }
    }

    for (; e + 3 < end; e += 4) {
        int2 r0 = recs[e];
        int2 r1 = recs[e + 1];
        int2 r2 = recs[e + 2];
        int2 r3 = recs[e + 3];
        ushort4 u0 = *(const ushort4*)(ftb + (size_t)r0.x * 256 + lane * 4);
        ushort4 u1 = *(const ushort4*)(ftb + (size_t)r1.x * 256 + lane * 4);
        ushort4 u2 = *(const ushort4*)(ftb + (size_t)r2.x * 256 + lane * 4);
        ushort4 u3 = *(const ushort4*)(ftb + (size_t)r3.x * 256 + lane * 4);
        const float v0 = __int_as_float(r0.y);
        const float v1 = __int_as_float(r1.y);
        const float v2 = __int_as_float(r2.y);
        const float v3 = __int_as_float(r3.y);
        ax += v0 * bf2f(u0.x); ay += v0 * bf2f(u0.y);
        az += v0 * bf2f(u0.z); aw += v0 * bf2f(u0.w);
        ax += v1 * bf2f(u1.x); ay += v1 * bf2f(u1.y);
        az += v1 * bf2f(u1.z); aw += v1 * bf2f(u1.w);
        ax += v2 * bf2f(u2.x); ay += v2 * bf2f(u2.y);
        az += v2 * bf2f(u2.z); aw += v2 * bf2f(u2.w);
        ax += v3 * bf2f(u3.x); ay += v3 * bf2f(u3.y);
        az += v3 * bf2f(u3.z); aw += v3 * bf2f(u3.w);
    }
    for (; e < end; e++) {
        int2 r0 = recs[e];
        ushort4 u0 = *(const ushort4*)(ftb + (size_t)r0.x * 256 + lane * 4);
        const float v0 = __int_as_float(r0.y);
        ax += v0 * bf2f(u0.x); ay += v0 * bf2f(u0.y);
        az += v0 * bf2f(u0.z); aw += v0 * bf2f(u0.w);
    }

    float4 res = make_float4(ax, ay, az, aw);
    *(float4*)(out + (size_t)n * 512 + 256 + lane * 4) = res;
}

// ---------------------------------------------------------------------------
extern "C" void kernel_launch(void* const* d_in, const int* in_sizes, int n_in,
                              void* d_out, int out_size, void* d_ws, size_t ws_size,
                              hipStream_t stream)
{
    const float* input = (const float*)d_in[0];
    const int*   esrc  = (const int*)d_in[1];
    const int*   edst  = (const int*)d_in[2];
    const float* eval  = (const float*)d_in[3];
    const float* W     = (const float*)d_in[4];
    float* out = (float*)d_out;

    char* ws = (char*)d_ws;
    unsigned short* Wt   = (unsigned short*)(ws);              // 131072 B
    int* counts          = (int*)(ws + 131072);                // 400000 B
    int* row_start       = (int*)(ws + 532480);                // 400004 B
    unsigned short* rank = (unsigned short*)(ws + 933888);     // 6.4e6 B
    int* partials        = (int*)(ws + 7334912);               // 2048 B
    int2* recs           = (int2*)(ws + 7337984);              // 25.6 MB
    unsigned short* ftb  = (unsigned short*)(ws + 7337984 + (size_t)N_EDGES * 8); // 51.2 MB

    hipMemsetAsync(counts, 0, N_NODES * sizeof(int), stream);

    wt_kernel<<<256, 256, 0, stream>>>(W, Wt);
    rank_hist_kernel<<<EDGE_NB, 256, 0, stream>>>(edst, counts, rank);
    scan1_kernel<<<SCAN_NB, 256, 0, stream>>>(counts, row_start, partials);
    scan2_kernel<<<1, 512, 0, stream>>>(partials);
    scan3_kernel<<<SCAN_NB, 256, 0, stream>>>(row_start, partials);
    fill_kernel<<<EDGE_NB, 256, 0, stream>>>(esrc, edst, eval, row_start, rank, recs);

    dim3 g((N_NODES + BM - 1) / BM);
    gemm_kernel<<<g, 256, 0, stream>>>(input, Wt, out, ftb);

    gather_kernel<<<(N_NODES + 3) / 4, 256, 0, stream>>>(row_start, recs, ftb, out);
}

// Round 2
// 733.170 us; speedup vs baseline: 1.0534x; 1.0143x over previous
//
#include <hip/hip_runtime.h>

#define N_NODES 100000
#define N_EDGES 3200000
#define F 256

#define BM 64
#define BN 256
#define BK 32

#define SCAN_NB ((N_NODES + 255) / 256)   // 391 blocks of 256
#define EDGE_NB4 (N_EDGES / 1024)         // 3125 blocks, 4 edges/thread, exact

typedef __attribute__((ext_vector_type(8))) short short8;
typedef __attribute__((ext_vector_type(4))) float f32x4;

__device__ inline unsigned short f2bf(float f) {
    unsigned int u = __float_as_uint(f);
    unsigned int r = (u + 0x7fffu + ((u >> 16) & 1u)) >> 16;
    return (unsigned short)r;
}

__device__ inline float bf2f(unsigned short b) {
    return __uint_as_float(((unsigned int)b) << 16);
}

// ---------------------------------------------------------------------------
// Weight transpose + convert: Wt[n][k] = bf16(W[k][n]). 256x256, tiny.
// ---------------------------------------------------------------------------
__global__ void wt_kernel(const float* __restrict__ W, unsigned short* __restrict__ Wt) {
    int idx = blockIdx.x * 256 + threadIdx.x;
    int n = idx >> 8;
    int k = idx & 255;
    Wt[n * 256 + k] = f2bf(W[k * 256 + n]);
}

// ---------------------------------------------------------------------------
// CSR build step 1: degree histogram AND per-edge rank (the atomic's return
// value). 4 edges/thread, vector loads, one 8B rank store.
// ---------------------------------------------------------------------------
__global__ __launch_bounds__(256)
void rank_hist_kernel(const int* __restrict__ dst, int* __restrict__ counts,
                      unsigned short* __restrict__ rank) {
    const int e0 = (blockIdx.x * 256 + threadIdx.x) * 4;
    const int4 d = *(const int4*)(dst + e0);
    ushort4 r;
    r.x = (unsigned short)atomicAdd(&counts[d.x], 1);
    r.y = (unsigned short)atomicAdd(&counts[d.y], 1);
    r.z = (unsigned short)atomicAdd(&counts[d.z], 1);
    r.w = (unsigned short)atomicAdd(&counts[d.w], 1);
    *(ushort4*)(rank + e0) = r;
}

// ---------------------------------------------------------------------------
// CSR build step 2a: per-block exclusive scan (256 elems/block) + block totals
// ---------------------------------------------------------------------------
__global__ __launch_bounds__(256)
void scan1_kernel(const int* __restrict__ counts, int* __restrict__ row_start,
                  int* __restrict__ partials) {
    __shared__ int s[256];
    const int t = threadIdx.x;
    const int i = blockIdx.x * 256 + t;
    int v = (i < N_NODES) ? counts[i] : 0;
    s[t] = v;
    __syncthreads();
#pragma unroll
    for (int off = 1; off < 256; off <<= 1) {
        int x = (t >= off) ? s[t - off] : 0;
        __syncthreads();
        if (t >= off) s[t] += x;
        __syncthreads();
    }
    if (i < N_NODES) row_start[i] = s[t] - v;
    if (t == 255) partials[blockIdx.x] = s[t];
}

// ---------------------------------------------------------------------------
// CSR build step 2b: scan the 391 block totals (single block, 512 threads)
// ---------------------------------------------------------------------------
__global__ __launch_bounds__(512)
void scan2_kernel(int* __restrict__ partials) {
    __shared__ int s[512];
    const int t = threadIdx.x;
    int v = (t < SCAN_NB) ? partials[t] : 0;
    s[t] = v;
    __syncthreads();
#pragma unroll
    for (int off = 1; off < 512; off <<= 1) {
        int x = (t >= off) ? s[t - off] : 0;
        __syncthreads();
        if (t >= off) s[t] += x;
        __syncthreads();
    }
    if (t < SCAN_NB) partials[t] = s[t] - v;
}

// ---------------------------------------------------------------------------
// CSR build step 2c: add block offsets.
// ---------------------------------------------------------------------------
__global__ __launch_bounds__(256)
void scan3_kernel(int* __restrict__ row_start, const int* __restrict__ partials) {
    const int i = blockIdx.x * 256 + threadIdx.x;
    if (i < N_NODES)
        row_start[i] += partials[blockIdx.x];
    if (i == 0) row_start[N_NODES] = N_EDGES;
}

// ---------------------------------------------------------------------------
// CSR build step 3: place packed (src, val) records at row_start[d] + rank[e].
// 4 edges/thread, vector loads, no atomics.
// ---------------------------------------------------------------------------
__global__ __launch_bounds__(256)
void fill_kernel(const int* __restrict__ src, const int* __restrict__ dst,
                 const float* __restrict__ val,
                 const int* __restrict__ row_start,
                 const unsigned short* __restrict__ rank,
                 int2* __restrict__ recs) {
    const int e0 = (blockIdx.x * 256 + threadIdx.x) * 4;
    const int4   s  = *(const int4*)(src + e0);
    const int4   d  = *(const int4*)(dst + e0);
    const float4 v  = *(const float4*)(val + e0);
    const ushort4 rk = *(const ushort4*)(rank + e0);
    recs[row_start[d.x] + (int)rk.x] = make_int2(s.x, __float_as_int(v.x));
    recs[row_start[d.y] + (int)rk.y] = make_int2(s.y, __float_as_int(v.y));
    recs[row_start[d.z] + (int)rk.z] = make_int2(s.z, __float_as_int(v.z));
    recs[row_start[d.w] + (int)rk.w] = make_int2(s.w, __float_as_int(v.w));
}

// ---------------------------------------------------------------------------
// GEMM: out[n, 0:256] = input[n, :] @ W  (fp32) + compact bf16 copy ftb[n][256].
// BM=64: 1563 blocks (3/CU, 2.03 rounds — kills the 782-block tail quantization).
// MFMA operands SWAPPED (mfma(b_frag, a_frag)) so the C-fragment is transposed:
// each lane holds 4 CONSECUTIVE COLUMNS of one row -> float4 out store +
// packed 8B bf16 ftb store. 8x fewer store instructions than scalar epilogue.
// ---------------------------------------------------------------------------
__global__ __launch_bounds__(256, 3)
void gemm_kernel(const float* __restrict__ A,
                 const unsigned short* __restrict__ Wt,
                 float* __restrict__ out,
                 unsigned short* __restrict__ ftb)
{
    __shared__ unsigned short As[BM * BK];   // 4 KB
    __shared__ unsigned short Bs[BN * BK];   // 16 KB

    const int tid   = threadIdx.x;
    const int lane  = tid & 63;
    const int wave  = tid >> 6;
    const int waveM = wave >> 1;             // 0..1 : 32-row half
    const int waveN = wave & 1;              // 0..1 : 128-col half
    const int rowBase = blockIdx.x * BM;

    f32x4 acc[2][8];
#pragma unroll
    for (int i = 0; i < 2; i++)
#pragma unroll
        for (int j = 0; j < 8; j++) acc[i][j] = (f32x4)0.0f;

    const int sr = tid >> 2;        // 0..63
    const int sk = (tid & 3) * 8;   // 0,8,16,24
    const int quad = lane >> 4;
    const int l16  = lane & 15;

    for (int kt = 0; kt < 8; kt++) {
        const int k0 = kt * BK;
        // A tile: 64 rows x 32 cols, fp32 -> bf16 convert (each thread: 1 row-chunk)
        {
            const int grow = rowBase + sr;
            short8 av;
            if (grow < N_NODES) {
                const float4* pa = (const float4*)(A + (size_t)grow * 256 + k0 + sk);
                float4 f0 = pa[0];
                float4 f1 = pa[1];
                av[0] = (short)f2bf(f0.x); av[1] = (short)f2bf(f0.y);
                av[2] = (short)f2bf(f0.z); av[3] = (short)f2bf(f0.w);
                av[4] = (short)f2bf(f1.x); av[5] = (short)f2bf(f1.y);
                av[6] = (short)f2bf(f1.z); av[7] = (short)f2bf(f1.w);
            } else {
                av = (short8)0;
            }
            *(short8*)(&As[sr * BK + sk]) = av;
        }
        // B tile: 256 rows (output cols) x 32
#pragma unroll
        for (int p = 0; p < 4; p++) {
            const int r = p * 64 + sr;
            const uint4 wv = *(const uint4*)(Wt + (size_t)r * 256 + k0 + sk);
            *(uint4*)(&Bs[r * BK + sk]) = wv;
        }
        __syncthreads();

        short8 af[2], bfr[8];
#pragma unroll
        for (int i = 0; i < 2; i++)
            af[i] = *(const short8*)(&As[(waveM * 32 + i * 16 + l16) * BK + quad * 8]);
#pragma unroll
        for (int j = 0; j < 8; j++)
            bfr[j] = *(const short8*)(&Bs[(waveN * 128 + j * 16 + l16) * BK + quad * 8]);
#pragma unroll
        for (int i = 0; i < 2; i++)
#pragma unroll
            for (int j = 0; j < 8; j++)
                acc[i][j] = __builtin_amdgcn_mfma_f32_16x16x32_bf16(
                    bfr[j], af[i], acc[i][j], 0, 0, 0);   // swapped -> C^T fragment
        __syncthreads();
    }

    // Epilogue: lane holds out[row][col..col+3] with row = ..+l16, col = ..+quad*4
#pragma unroll
    for (int i = 0; i < 2; i++) {
        const int row = rowBase + waveM * 32 + i * 16 + l16;
        if (row < N_NODES) {
#pragma unroll
            for (int j = 0; j < 8; j++) {
                const int col = waveN * 128 + j * 16 + quad * 4;
                f32x4 v = acc[i][j];
                *(f32x4*)(out + (size_t)row * 512 + col) = v;
                unsigned int p0 = ((unsigned int)f2bf(v[1]) << 16) | f2bf(v[0]);
                unsigned int p1 = ((unsigned int)f2bf(v[3]) << 16) | f2bf(v[2]);
                *(uint2*)(ftb + (size_t)row * 256 + col) = make_uint2(p0, p1);
            }
        }
    }
}

// ---------------------------------------------------------------------------
// Gather: one wave per dst node. out[n, 256:512] = sum_e val_e * ftb[src_e]
// 8-edge unroll + recs prefetch. At the random-access memory roofline
// (~3.5-4 TB/s on the miss path) — unchanged from round 1.
// ---------------------------------------------------------------------------
__global__ __launch_bounds__(256)
void gather_kernel(const int* __restrict__ row_start,
                   const int2* __restrict__ recs,
                   const unsigned short* __restrict__ ftb,
                   float* __restrict__ out)
{
    const int n = blockIdx.x * 4 + (threadIdx.x >> 6);
    if (n >= N_NODES) return;
    const int lane = threadIdx.x & 63;

    const int beg = row_start[n];
    const int end = row_start[n + 1];

    float ax = 0.f, ay = 0.f, az = 0.f, aw = 0.f;

    int e = beg;

    if (e + 7 < end) {
        int2 r[8];
#pragma unroll
        for (int q = 0; q < 8; q++) r[q] = recs[e + q];
        while (true) {
            const int en = e + 8;
            const bool moreN = (en + 7 < end);
            int2 rn[8];
            if (moreN) {
#pragma unroll
                for (int q = 0; q < 8; q++) rn[q] = recs[en + q];
            }
            ushort4 u[8];
#pragma unroll
            for (int q = 0; q < 8; q++)
                u[q] = *(const ushort4*)(ftb + (size_t)r[q].x * 256 + lane * 4);
#pragma unroll
            for (int q = 0; q < 8; q++) {
                const float v = __int_as_float(r[q].y);
                ax += v * bf2f(u[q].x); ay += v * bf2f(u[q].y);
                az += v * bf2f(u[q].z); aw += v * bf2f(u[q].w);
            }
            e = en;
            if (!moreN) break;
#pragma unroll
            for (int q = 0; q < 8; q++) r[q] = rn[q];
        }
    }

    for (; e + 3 < end; e += 4) {
        int2 r0 = recs[e];
        int2 r1 = recs[e + 1];
        int2 r2 = recs[e + 2];
        int2 r3 = recs[e + 3];
        ushort4 u0 = *(const ushort4*)(ftb + (size_t)r0.x * 256 + lane * 4);
        ushort4 u1 = *(const ushort4*)(ftb + (size_t)r1.x * 256 + lane * 4);
        ushort4 u2 = *(const ushort4*)(ftb + (size_t)r2.x * 256 + lane * 4);
        ushort4 u3 = *(const ushort4*)(ftb + (size_t)r3.x * 256 + lane * 4);
        const float v0 = __int_as_float(r0.y);
        const float v1 = __int_as_float(r1.y);
        const float v2 = __int_as_float(r2.y);
        const float v3 = __int_as_float(r3.y);
        ax += v0 * bf2f(u0.x); ay += v0 * bf2f(u0.y);
        az += v0 * bf2f(u0.z); aw += v0 * bf2f(u0.w);
        ax += v1 * bf2f(u1.x); ay += v1 * bf2f(u1.y);
        az += v1 * bf2f(u1.z); aw += v1 * bf2f(u1.w);
        ax += v2 * bf2f(u2.x); ay += v2 * bf2f(u2.y);
        az += v2 * bf2f(u2.z); aw += v2 * bf2f(u2.w);
        ax += v3 * bf2f(u3.x); ay += v3 * bf2f(u3.y);
        az += v3 * bf2f(u3.z); aw += v3 * bf2f(u3.w);
    }
    for (; e < end; e++) {
        int2 r0 = recs[e];
        ushort4 u0 = *(const ushort4*)(ftb + (size_t)r0.x * 256 + lane * 4);
        const float v0 = __int_as_float(r0.y);
        ax += v0 * bf2f(u0.x); ay += v0 * bf2f(u0.y);
        az += v0 * bf2f(u0.z); aw += v0 * bf2f(u0.w);
    }

    float4 res = make_float4(ax, ay, az, aw);
    *(float4*)(out + (size_t)n * 512 + 256 + lane * 4) = res;
}

// ---------------------------------------------------------------------------
extern "C" void kernel_launch(void* const* d_in, const int* in_sizes, int n_in,
                              void* d_out, int out_size, void* d_ws, size_t ws_size,
                              hipStream_t stream)
{
    const float* input = (const float*)d_in[0];
    const int*   esrc  = (const int*)d_in[1];
    const int*   edst  = (const int*)d_in[2];
    const float* eval  = (const float*)d_in[3];
    const float* W     = (const float*)d_in[4];
    float* out = (float*)d_out;

    char* ws = (char*)d_ws;
    unsigned short* Wt   = (unsigned short*)(ws);              // 131072 B
    int* counts          = (int*)(ws + 131072);                // 400000 B
    int* row_start       = (int*)(ws + 532480);                // 400004 B
    unsigned short* rank = (unsigned short*)(ws + 933888);     // 6.4e6 B
    int* partials        = (int*)(ws + 7334912);               // 2048 B
    int2* recs           = (int2*)(ws + 7337984);              // 25.6 MB
    unsigned short* ftb  = (unsigned short*)(ws + 7337984 + (size_t)N_EDGES * 8); // 51.2 MB

    hipMemsetAsync(counts, 0, N_NODES * sizeof(int), stream);

    wt_kernel<<<256, 256, 0, stream>>>(W, Wt);
    rank_hist_kernel<<<EDGE_NB4, 256, 0, stream>>>(edst, counts, rank);
    scan1_kernel<<<SCAN_NB, 256, 0, stream>>>(counts, row_start, partials);
    scan2_kernel<<<1, 512, 0, stream>>>(partials);
    scan3_kernel<<<SCAN_NB, 256, 0, stream>>>(row_start, partials);
    fill_kernel<<<EDGE_NB4, 256, 0, stream>>>(esrc, edst, eval, row_start, rank, recs);

    dim3 g((N_NODES + BM - 1) / BM);
    gemm_kernel<<<g, 256, 0, stream>>>(input, Wt, out, ftb);

    gather_kernel<<<(N_NODES + 3) / 4, 256, 0, stream>>>(row_start, recs, ftb, out);
}